// Round 1
// baseline (328.439 us; speedup 1.0000x reference)
//
#include <hip/hip_runtime.h>
#include <hip/hip_fp8.h>
#include <math.h>

#define N_ROWS 8192
#define IN_F   512
#define RFF    2048
#define OUT_F  1000
#define OUT_PAD 1024
#define INV_RFF_SCALAR 0.03125f
#define MEAN_FIELD 25.0f
#define PHI_NT 24   /* K = 1536 (concat hh|hl|lh), BK = 64 */

typedef __attribute__((ext_vector_type(8))) short short8;
typedef __attribute__((ext_vector_type(4))) float f32x4;
typedef __attribute__((ext_vector_type(2))) long long2v;

// ---------- bf16 helpers (RTN-even) ----------
__device__ __forceinline__ unsigned short f32_to_bf16(float f) {
    unsigned u = __float_as_uint(f);
    unsigned r = 0x7FFFu + ((u >> 16) & 1u);
    return (unsigned short)((u + r) >> 16);
}
__device__ __forceinline__ float bf16_to_f32(unsigned short h) {
    return __uint_as_float(((unsigned)h) << 16);
}
__device__ __forceinline__ unsigned char f32_to_fp8(float x) {
    __hip_fp8_e4m3 q(x);           // OCP e4m3fn, HW RNE convert
    return (unsigned char)q.__x;
}

// fp8 permuted packing within each 64-element k-block:
// pos(k) = (k & ~63) + quad*16 + s*8 + j   (quad=(k>>3)&3, s=(k>>5)&1, j=k&7)
__device__ __forceinline__ int perm64(int k) {
    return (k & ~63) | (((k >> 3) & 3) << 4) | (((k >> 5) & 1) << 3) | (k & 7);
}

// ---- bf16 staging, K=64 tile (pred): 1024 chunks, q = rt*128 + c*16 + r ----
__device__ __forceinline__ void stage_tile64(const unsigned short* __restrict__ X,
                                             int r0, int k0, unsigned char* lds,
                                             int w, int lane) {
    #pragma unroll
    for (int h = 0; h < 4; ++h) {
        int qb = h * 256 + w * 64;
        int q = qb + lane;
        int rt = q >> 7, c = (q >> 4) & 7, r = q & 15;
        const void* g = X + (size_t)(r0 + rt * 16 + r) * RFF + k0 + c * 8;
        __builtin_amdgcn_global_load_lds(
            (const __attribute__((address_space(1))) void*)g,
            (__attribute__((address_space(3))) void*)(lds + qb * 16),
            16, 0, 0);
    }
}

// ---- fp8 staging, K=128-byte tile (diag) ----
__device__ __forceinline__ void stage_tile8(const unsigned char* __restrict__ X,
                                            int r0, int k0b, unsigned char* lds,
                                            int w, int lane) {
    #pragma unroll
    for (int h = 0; h < 4; ++h) {
        int qb = h * 256 + w * 64;
        int q = qb + lane;
        int rt = q >> 7, c = (q >> 4) & 7, r = q & 15;
        const void* g = X + (size_t)(r0 + rt * 16 + r) * RFF + k0b + c * 16;
        __builtin_amdgcn_global_load_lds(
            (const __attribute__((address_space(1))) void*)g,
            (__attribute__((address_space(3))) void*)(lds + qb * 16),
            16, 0, 0);
    }
}

// ---------------- conversion kernels ----------------
__global__ __launch_bounds__(256) void conv_split_kernel(
    const float* __restrict__ X, unsigned short* __restrict__ H,
    unsigned short* __restrict__ L, int n4)
{
    int i = blockIdx.x * 256 + threadIdx.x;
    if (i >= n4) return;
    float4 v = ((const float4*)X)[i];
    ushort4 h, l;
    h.x = f32_to_bf16(v.x); l.x = f32_to_bf16(v.x - bf16_to_f32(h.x));
    h.y = f32_to_bf16(v.y); l.y = f32_to_bf16(v.y - bf16_to_f32(h.y));
    h.z = f32_to_bf16(v.z); l.z = f32_to_bf16(v.z - bf16_to_f32(h.z));
    h.w = f32_to_bf16(v.w); l.w = f32_to_bf16(v.w - bf16_to_f32(h.w));
    ((ushort4*)H)[i] = h;
    ((ushort4*)L)[i] = l;
}

__global__ __launch_bounds__(256) void conv_covu8_kernel(
    const float* __restrict__ X, unsigned char* __restrict__ O)
{
    int i = blockIdx.x * 256 + threadIdx.x;   // float4 group
    int base = i * 4;
    int row = base >> 11;          // n
    int col = base & 2047;         // k of first component
    int bn = row >> 7, bk = col >> 7;
    float w = (bk < bn) ? 16.0f : (bk == bn ? 8.0f : 0.0f);
    float4 v = ((const float4*)X)[i];
    float w0 = (col + 0 == row) ? 0.0f : w;
    float w1 = (col + 1 == row) ? 0.0f : w;
    float w2 = (col + 2 == row) ? 0.0f : w;
    float w3 = (col + 3 == row) ? 0.0f : w;
    uchar4 o;
    o.x = f32_to_fp8(v.x * w0); o.y = f32_to_fp8(v.y * w1);
    o.z = f32_to_fp8(v.z * w2); o.w = f32_to_fp8(v.w * w3);
    *(uchar4*)(O + (size_t)row * RFF + perm64(col)) = o;
}

__global__ __launch_bounds__(256) void conv_covd_kernel(
    const float* __restrict__ X, float* __restrict__ Cd)
{
    int i = blockIdx.x * 256 + threadIdx.x;
    if (i < RFF) Cd[i] = X[(size_t)i * RFF + i];
}

__global__ __launch_bounds__(256) void conv_phi8_kernel(
    const unsigned short* __restrict__ Phi16, unsigned char* __restrict__ Phi8)
{
    int i = blockIdx.x * 256 + threadIdx.x;
    int base = i * 4;
    int row = base >> 11;
    int col = base & 2047;
    ushort4 v = ((const ushort4*)Phi16)[i];
    uchar4 o;
    o.x = f32_to_fp8(bf16_to_f32(v.x) * 32.0f);
    o.y = f32_to_fp8(bf16_to_f32(v.y) * 32.0f);
    o.z = f32_to_fp8(bf16_to_f32(v.z) * 32.0f);
    o.w = f32_to_fp8(bf16_to_f32(v.w) * 32.0f);
    *(uchar4*)(Phi8 + (size_t)row * RFF + perm64(col)) = o;
}

__global__ __launch_bounds__(256) void conv_lw_kernel(
    const float* __restrict__ Lw, unsigned short* __restrict__ O)
{
    int i = blockIdx.x * 256 + threadIdx.x;
    int base = i * 4;
    int row = base >> 11;
    ushort4 o;
    if (row < OUT_F) {
        float4 v = ((const float4*)Lw)[i];
        o.x = f32_to_bf16(v.x); o.y = f32_to_bf16(v.y);
        o.z = f32_to_bf16(v.z); o.w = f32_to_bf16(v.w);
    } else {
        o.x = o.y = o.z = o.w = 0;
    }
    ((ushort4*)O)[i] = o;
}

__global__ __launch_bounds__(256) void conv_wt_kernel(
    const float* __restrict__ W, unsigned short* __restrict__ TH,
    unsigned short* __restrict__ TL)
{
    __shared__ float tile[64][65];
    const int tid = threadIdx.x;
    const int n0 = blockIdx.x * 64;
    const int k0 = blockIdx.y * 64;
    #pragma unroll
    for (int i = 0; i < 16; ++i) {
        int e = i * 256 + tid;
        int r = e >> 6, c = e & 63;
        tile[r][c] = W[(size_t)(k0 + r) * RFF + n0 + c];
    }
    __syncthreads();
    #pragma unroll
    for (int i = 0; i < 16; ++i) {
        int e = i * 256 + tid;
        int r = e >> 6, c = e & 63;
        float v = tile[c][r];
        unsigned short h = f32_to_bf16(v);
        unsigned short l = f32_to_bf16(v - bf16_to_f32(h));
        TH[(size_t)(n0 + r) * IN_F + k0 + c] = h;
        TL[(size_t)(n0 + r) * IN_F + k0 + c] = l;
    }
}

// =====================================================================
// Kernel 1 (NEW): Phi = cos(D@W + b)/32 as ONE bf16 GEMM, K-concat 1536:
//   A' = [Dh | Dh | Dl]  (8192 x 1536)
//   B' = [Wh | Wl | Wh]  (2048 x 1536, B^T layout)
// 256x256 tile, BK=64, 512 thr (8 waves 2Mx4N, 128x64 out/wave),
// 8-phase-style schedule: per-phase {12 ds_read_b128; 2 global_load_lds;
// barrier; setprio(1); 16 MFMA; setprio(0); barrier}; counted vmcnt(4)
// once per K-tile (never 0 in steady state). LDS chunk layout is the
// proven zero-conflict [RT][kc][r] pattern; staging targets only regions
// freed by an earlier phase's end barrier (race-free by construction).
// =====================================================================

__device__ __forceinline__ void gload16u(const void* g, unsigned short* lds) {
    __builtin_amdgcn_global_load_lds(
        (const __attribute__((address_space(1))) void*)g,
        (__attribute__((address_space(3))) void*)lds, 16, 0, 0);
}

// A-group: 64 rows (quarter Qa of half h), full BK=64. 1 load/thread.
// LDS layout (per 32KB buf): RT*2048 + c*256 + r*16 bytes, RT=row/16,
// c = k-chunk of 8, r = row%16. Wave-uniform LDS base + lane*16.
__device__ __forceinline__ void stageA_g(const unsigned short* __restrict__ src,
                                         int r0, int kk, unsigned short* ldsbuf,
                                         int Qa, int h, int w, int lane) {
    int q   = w * 64 + lane;
    int RTl = h * 8 + Qa * 4 + (q >> 7);
    int c   = (q >> 4) & 7, r = q & 15;
    const void* g = src + (size_t)(r0 + RTl * 16 + r) * IN_F + kk + c * 8;
    int RTu = h * 8 + Qa * 4 + (w >> 1);
    int cu  = (w & 1) * 4;
    gload16u(g, ldsbuf + RTu * 1024 + cu * 128);
}

// B-group: the 64 rows (of half h) consumed by quadrant nh:
// within-half RT' in {nh*2, nh*2+1, 4+nh*2, 4+nh*2+1}. 1 load/thread.
__device__ __forceinline__ void stageB_g(const unsigned short* __restrict__ src,
                                         int cc0, int kk, unsigned short* ldsbuf,
                                         int nh, int h, int w, int lane) {
    int q    = w * 64 + lane;
    int i    = q >> 7;                              // uniform per wave
    int RTp  = (i >> 1) * 4 + nh * 2 + (i & 1);
    int c    = (q >> 4) & 7, r = q & 15;
    const void* g = src + (size_t)(cc0 + h * 128 + RTp * 16 + r) * IN_F + kk + c * 8;
    int iu   = w >> 1;
    int RTpu = (iu >> 1) * 4 + nh * 2 + (iu & 1);
    int RTu  = h * 8 + RTpu;
    int cu   = (w & 1) * 4;
    gload16u(g, ldsbuf + RTu * 1024 + cu * 128);
}

#define BAR() do { asm volatile("" ::: "memory"); \
                   __builtin_amdgcn_s_barrier();  \
                   asm volatile("" ::: "memory"); } while (0)
#define WAITVM(N) asm volatile("s_waitcnt vmcnt(" #N ")" ::: "memory")

// One phase: quadrant (mh,nh). Reads 8 A-frags + 4 B-frags, issues this
// phase's staging (ISSUES), barrier, 16 MFMA under setprio, barrier.
#define PHI_PHASE(mh, nh, ...) do {                                            \
    short8 fa[4][2], fb[2][2];                                                 \
    _Pragma("unroll")                                                          \
    for (int i_ = 0; i_ < 4; ++i_) {                                           \
        fa[i_][0] = *(const short8*)(A + ((wm)*8 + (mh)*4 + i_) * 1024         \
                                       + quad * 128 + ln * 8);                 \
        fa[i_][1] = *(const short8*)(A + ((wm)*8 + (mh)*4 + i_) * 1024         \
                                       + 512 + quad * 128 + ln * 8);           \
    }                                                                          \
    _Pragma("unroll")                                                          \
    for (int j_ = 0; j_ < 2; ++j_) {                                           \
        fb[j_][0] = *(const short8*)(B + ((wn)*4 + (nh)*2 + j_) * 1024         \
                                       + quad * 128 + ln * 8);                 \
        fb[j_][1] = *(const short8*)(B + ((wn)*4 + (nh)*2 + j_) * 1024         \
                                       + 512 + quad * 128 + ln * 8);           \
    }                                                                          \
    __VA_ARGS__;                                                               \
    BAR();                                                                     \
    __builtin_amdgcn_s_setprio(1);                                             \
    _Pragma("unroll")                                                          \
    for (int s_ = 0; s_ < 2; ++s_)                                             \
        _Pragma("unroll")                                                      \
        for (int i_ = 0; i_ < 4; ++i_)                                         \
            _Pragma("unroll")                                                  \
            for (int j_ = 0; j_ < 2; ++j_)                                     \
                acc[(mh)*4 + i_][(nh)*2 + j_] =                                \
                    __builtin_amdgcn_mfma_f32_16x16x32_bf16(                   \
                        fa[i_][s_], fb[j_][s_],                                \
                        acc[(mh)*4 + i_][(nh)*2 + j_], 0, 0, 0);               \
    __builtin_amdgcn_s_setprio(0);                                             \
    BAR();                                                                     \
} while (0)

__global__ __launch_bounds__(512, 2) void phi_mfma8p_kernel(
    const unsigned short* __restrict__ Dh, const unsigned short* __restrict__ Dl,
    const unsigned short* __restrict__ Wth, const unsigned short* __restrict__ Wtl,
    const float* __restrict__ bias, unsigned short* __restrict__ Phi)
{
    __shared__ unsigned short ldsA[2 * 16384];   // 64 KiB (2 bufs x 256x64 bf16)
    __shared__ unsigned short ldsB[2 * 16384];   // 64 KiB
    const int tid = threadIdx.x;
    const int w = tid >> 6, lane = tid & 63;
    const int wm = w >> 2, wn = w & 3;
    const int quad = lane >> 4, ln = lane & 15;

    // XCD-contiguous swizzle: each XCD owns one bn column (B panel L2-resident)
    const int bid = blockIdx.x;
    const int wg = ((bid & 7) << 5) | (bid >> 3);
    const int r0 = (wg & 31) * 256;
    const int c0 = (wg >> 5) * 256;

    f32x4 acc[8][4];
    #pragma unroll
    for (int i = 0; i < 8; ++i)
        #pragma unroll
        for (int j = 0; j < 4; ++j)
            acc[i][j] = (f32x4)(0.0f);

    // ---- prologue: tile 0 complete (8 groups) + tile 1 first half (4) ----
    stageA_g(Dh,  r0, 0, ldsA, 0, 0, w, lane);
    stageA_g(Dh,  r0, 0, ldsA, 0, 1, w, lane);
    stageA_g(Dh,  r0, 0, ldsA, 1, 0, w, lane);
    stageA_g(Dh,  r0, 0, ldsA, 1, 1, w, lane);
    stageB_g(Wth, c0, 0, ldsB, 0, 0, w, lane);
    stageB_g(Wth, c0, 0, ldsB, 0, 1, w, lane);
    stageB_g(Wth, c0, 0, ldsB, 1, 0, w, lane);
    stageB_g(Wth, c0, 0, ldsB, 1, 1, w, lane);
    stageA_g(Dh,  r0, 64, ldsA + 16384, 0, 0, w, lane);
    stageA_g(Dh,  r0, 64, ldsA + 16384, 0, 1, w, lane);
    stageB_g(Wth, c0, 64, ldsB + 16384, 0, 0, w, lane);
    stageB_g(Wth, c0, 64, ldsB + 16384, 0, 1, w, lane);
    WAITVM(4);       // tile 0 landed; tile 1's 4 remain in flight
    BAR();

    for (int t = 0; t < PHI_NT; ++t) {
        const int buf = t & 1;
        const unsigned short* A = ldsA + buf * 16384;
        const unsigned short* B = ldsB + buf * 16384;
        unsigned short* curA = ldsA + buf * 16384;          // tile t+2 target
        unsigned short* curB = ldsB + buf * 16384;
        unsigned short* othA = ldsA + (buf ^ 1) * 16384;    // tile t+1 target
        unsigned short* othB = ldsB + (buf ^ 1) * 16384;
        const bool has1 = (t + 1) < PHI_NT, has2 = (t + 2) < PHI_NT;
        const int k1 = (t + 1) * 64, k2 = (t + 2) * 64;
        const int kk1 = k1 & 511, kk2 = k2 & 511;
        const unsigned short* A1 = (k1 >= 1024) ? Dl : Dh;
        const unsigned short* B1 = (k1 >= 1024) ? Wth : (k1 >= 512 ? Wtl : Wth);
        const unsigned short* A2 = (k2 >= 1024) ? Dl : Dh;
        const unsigned short* B2 = (k2 >= 1024) ? Wth : (k2 >= 512 ? Wtl : Wth);

        // P1: quadrant (0,0); issue t+1's A quarter-1 (regions free since t-1.P4)
        PHI_PHASE(0, 0,
            if (has1) { stageA_g(A1, r0, kk1, othA, 1, 0, w, lane);
                        stageA_g(A1, r0, kk1, othA, 1, 1, w, lane); });
        // P2: quadrant (0,1); issue t+1's B nh1 groups
        PHI_PHASE(0, 1,
            if (has1) { stageB_g(B1, c0, kk1, othB, 1, 0, w, lane);
                        stageB_g(B1, c0, kk1, othB, 1, 1, w, lane); });
        // P3: quadrant (1,0); issue t+2's A quarter-0 (freed by P2 end barrier)
        PHI_PHASE(1, 0,
            if (has2) { stageA_g(A2, r0, kk2, curA, 0, 0, w, lane);
                        stageA_g(A2, r0, kk2, curA, 0, 1, w, lane); });
        // P4: quadrant (1,1); issue t+2's B nh0 (freed by P3 end barrier);
        // counted wait: all of tile t+1 landed, t+2's 4 stay in flight.
        PHI_PHASE(1, 1,
            if (has2) { stageB_g(B2, c0, kk2, curB, 0, 0, w, lane);
                        stageB_g(B2, c0, kk2, curB, 0, 1, w, lane);
                        WAITVM(4); }
            else if (has1) { WAITVM(0); });
    }

    // ---- epilogue: z -> cos(z)/32 -> bf16 ----
    float bv[4];
    #pragma unroll
    for (int nt = 0; nt < 4; ++nt)
        bv[nt] = bias[c0 + wn * 64 + nt * 16 + ln];
    #pragma unroll
    for (int mt = 0; mt < 8; ++mt)
        #pragma unroll
        for (int nt = 0; nt < 4; ++nt) {
            int col = c0 + wn * 64 + nt * 16 + ln;
            #pragma unroll
            for (int reg = 0; reg < 4; ++reg) {
                int row = r0 + wm * 128 + mt * 16 + quad * 4 + reg;
                float z = acc[mt][nt][reg] + bv[nt];
                float p = __cosf(z) * INV_RFF_SCALAR;
                Phi[(size_t)row * RFF + col] = f32_to_bf16(p);
            }
        }
}

// ------- Kernel 2: diag via fp8 (off-diag) + exact diagonal; triangular K -------
__global__ __launch_bounds__(256) void diag8_kernel(
    const unsigned char* __restrict__ Phi8, const unsigned char* __restrict__ CovU8,
    const unsigned short* __restrict__ Phi16, const float* __restrict__ Cd,
    float* __restrict__ diag)
{
    __shared__ __align__(16) unsigned char ldsA[16384];
    __shared__ __align__(16) unsigned char ldsB[16384];
    const int tid = threadIdx.x;
    const int w = tid >> 6, lane = tid & 63;
    const int wm = w >> 1, wn = w & 1;
    const int quad = lane >> 4, ln = lane & 15;
    const int J = 15 - blockIdx.x;
    const int r0 = blockIdx.y * 128;
    const int c0 = J * 128;
    const int kmax = (J + 1) * 128;

    f32x4 acc[4][4];
    #pragma unroll
    for (int i = 0; i < 4; ++i)
        #pragma unroll
        for (int j = 0; j < 4; ++j)
            acc[i][j] = (f32x4)(0.0f);

    for (int k0 = 0; k0 < kmax; k0 += 128) {
        __syncthreads();
        stage_tile8(Phi8,  r0, k0, ldsA, w, lane);
        stage_tile8(CovU8, c0, k0, ldsB, w, lane);
        __syncthreads();

        #pragma unroll
        for (int kb = 0; kb < 2; ++kb) {
            long2v fa[4], fb[4];
            #pragma unroll
            for (int t = 0; t < 4; ++t) {
                fa[t] = *(const long2v*)(ldsA + (((wm * 4 + t) * 128 + (kb * 4 + quad) * 16 + ln) << 4));
                fb[t] = *(const long2v*)(ldsB + (((wn * 4 + t) * 128 + (kb * 4 + quad) * 16 + ln) << 4));
            }
            #pragma unroll
            for (int mt = 0; mt < 4; ++mt)
                #pragma unroll
                for (int nt = 0; nt < 4; ++nt)
                    acc[mt][nt] = __builtin_amdgcn_mfma_f32_16x16x32_fp8_fp8(
                        fa[mt].x, fb[nt].x, acc[mt][nt], 0, 0, 0);
            #pragma unroll
            for (int mt = 0; mt < 4; ++mt)
                #pragma unroll
                for (int nt = 0; nt < 4; ++nt)
                    acc[mt][nt] = __builtin_amdgcn_mfma_f32_16x16x32_fp8_fp8(
                        fa[mt].y, fb[nt].y, acc[mt][nt], 0, 0, 0);
        }
    }

    float cd[4];
    #pragma unroll
    for (int nt = 0; nt < 4; ++nt)
        cd[nt] = 256.0f * Cd[c0 + wn * 64 + nt * 16 + ln];
    #pragma unroll
    for (int mt = 0; mt < 4; ++mt) {
        float psum[4] = {0.f, 0.f, 0.f, 0.f};
        #pragma unroll
        for (int nt = 0; nt < 4; ++nt) {
            int col = c0 + wn * 64 + nt * 16 + ln;
            #pragma unroll
            for (int reg = 0; reg < 4; ++reg) {
                int row = r0 + wm * 64 + mt * 16 + quad * 4 + reg;
                float pv = bf16_to_f32(Phi16[(size_t)row * RFF + col]);
                psum[reg] = fmaf(fmaf(cd[nt], pv, acc[mt][nt][reg]), pv, psum[reg]);
            }
        }
        #pragma unroll
        for (int off = 1; off < 16; off <<= 1)
            #pragma unroll
            for (int reg = 0; reg < 4; ++reg)
                psum[reg] += __shfl_xor(psum[reg], off, 16);
        if (ln == 0) {
            #pragma unroll
            for (int reg = 0; reg < 4; ++reg) {
                int row = r0 + wm * 64 + mt * 16 + quad * 4 + reg;
                atomicAdd(&diag[row], psum[reg] * (1.0f / 256.0f));
            }
        }
    }
}

// ---- Kernel 3: out = (Phi@LwT + Lb) / sqrt(1+25*diag), bf16, K-step 64 ----
__global__ __launch_bounds__(256) void pred_mfma_kernel(
    const unsigned short* __restrict__ Phi, const unsigned short* __restrict__ Lw,
    const float* __restrict__ Lb, const float* __restrict__ diag,
    float* __restrict__ out)
{
    __shared__ __align__(16) unsigned char ldsA[16384];
    __shared__ __align__(16) unsigned char ldsB[16384];
    const int tid = threadIdx.x;
    const int w = tid >> 6, lane = tid & 63;
    const int wm = w >> 1, wn = w & 1;
    const int quad = lane >> 4, ln = lane & 15;
    const int r0 = blockIdx.y * 128;
    const int c0 = blockIdx.x * 128;

    f32x4 acc[4][4];
    #pragma unroll
    for (int i = 0; i < 4; ++i)
        #pragma unroll
        for (int j = 0; j < 4; ++j)
            acc[i][j] = (f32x4)(0.0f);

    for (int k0 = 0; k0 < RFF; k0 += 64) {
        __syncthreads();
        stage_tile64(Phi, r0, k0, ldsA, w, lane);
        stage_tile64(Lw,  c0, k0, ldsB, w, lane);
        __syncthreads();

        #pragma unroll
        for (int s = 0; s < 2; ++s) {
            short8 fa[4], fb[4];
            #pragma unroll
            for (int t = 0; t < 4; ++t) {
                fa[t] = *(const short8*)(ldsA + (((wm * 4 + t) * 128 + (s * 4 + quad) * 16 + ln) << 4));
                fb[t] = *(const short8*)(ldsB + (((wn * 4 + t) * 128 + (s * 4 + quad) * 16 + ln) << 4));
            }
            #pragma unroll
            for (int mt = 0; mt < 4; ++mt)
                #pragma unroll
                for (int nt = 0; nt < 4; ++nt)
                    acc[mt][nt] = __builtin_amdgcn_mfma_f32_16x16x32_bf16(
                        fa[mt], fb[nt], acc[mt][nt], 0, 0, 0);
        }
    }

    #pragma unroll
    for (int mt = 0; mt < 4; ++mt) {
        float s[4];
        #pragma unroll
        for (int reg = 0; reg < 4; ++reg) {
            int row = r0 + wm * 64 + mt * 16 + quad * 4 + reg;
            s[reg] = 1.0f / sqrtf(1.0f + MEAN_FIELD * diag[row]);
        }
        #pragma unroll
        for (int nt = 0; nt < 4; ++nt) {
            int col = c0 + wn * 64 + nt * 16 + ln;
            if (col < OUT_F) {
                float bv = Lb[col];
                #pragma unroll
                for (int reg = 0; reg < 4; ++reg) {
                    int row = r0 + wm * 64 + mt * 16 + quad * 4 + reg;
                    out[(size_t)row * OUT_F + col] = (acc[mt][nt][reg] + bv) * s[reg];
                }
            }
        }
    }
}

extern "C" void kernel_launch(void* const* d_in, const int* in_sizes, int n_in,
                              void* d_out, int out_size, void* d_ws, size_t ws_size,
                              hipStream_t stream) {
    const float* D    = (const float*)d_in[0];
    const float* W    = (const float*)d_in[1];
    const float* bias = (const float*)d_in[2];
    const float* Lw   = (const float*)d_in[3];
    const float* Lb   = (const float*)d_in[4];
    const float* cov  = (const float*)d_in[5];
    float* out = (float*)d_out;

    char* p = (char*)d_ws;
    unsigned short* Phi16 = (unsigned short*)p;  p += (size_t)N_ROWS * RFF * 2;   // 32 MiB
    unsigned char*  Phi8  = (unsigned char*)p;   // alias of Dh+Dl region (16 MiB)
    unsigned short* Dh    = (unsigned short*)p;  p += (size_t)N_ROWS * IN_F * 2;  // 8 MiB
    unsigned short* Dl    = (unsigned short*)p;  p += (size_t)N_ROWS * IN_F * 2;  // 8 MiB
    unsigned short* Wth   = (unsigned short*)p;  p += (size_t)RFF * IN_F * 2;     // 2 MiB
    unsigned short* Wtl   = (unsigned short*)p;  p += (size_t)RFF * IN_F * 2;     // 2 MiB
    unsigned short* Lw16  = (unsigned short*)p;  p += (size_t)OUT_PAD * RFF * 2;  // 4 MiB
    unsigned char*  CovU8 = (unsigned char*)p;                                    // 4 MiB used
    float*          Cd    = (float*)(p + (size_t)RFF * RFF);                      // 8 KiB (in pad)
    p += (size_t)RFF * RFF * 2;                                                   // 8 MiB region
    float* diag           = (float*)p;                                            // 32 KiB

    hipMemsetAsync(diag, 0, N_ROWS * sizeof(float), stream);

    dim3 blk(256);
    conv_split_kernel<<<dim3((N_ROWS * IN_F / 4 + 255) / 256), blk, 0, stream>>>(D, Dh, Dl, N_ROWS * IN_F / 4);
    conv_wt_kernel<<<dim3(RFF / 64, IN_F / 64), blk, 0, stream>>>(W, Wth, Wtl);
    conv_lw_kernel<<<dim3(OUT_PAD * RFF / 4 / 256), blk, 0, stream>>>(Lw, Lw16);
    conv_covu8_kernel<<<dim3(RFF * RFF / 4 / 256), blk, 0, stream>>>(cov, CovU8);
    conv_covd_kernel<<<dim3(RFF / 256), blk, 0, stream>>>(cov, Cd);

    phi_mfma8p_kernel<<<dim3(256), dim3(512), 0, stream>>>(Dh, Dl, Wth, Wtl, bias, Phi16);
    conv_phi8_kernel<<<dim3(N_ROWS * RFF / 4 / 256), blk, 0, stream>>>(Phi16, Phi8);

    diag8_kernel<<<dim3(16, N_ROWS / 128), blk, 0, stream>>>(Phi8, CovU8, Phi16, Cd, diag);
    pred_mfma_kernel<<<dim3(OUT_PAD / 128, N_ROWS / 128), blk, 0, stream>>>(Phi16, Lw16, Lb, diag, out);
}

// Round 2
// 313.688 us; speedup vs baseline: 1.0470x; 1.0470x over previous
//
#include <hip/hip_runtime.h>
#include <hip/hip_fp8.h>
#include <math.h>

#define N_ROWS 8192
#define IN_F   512
#define RFF    2048
#define OUT_F  1000
#define OUT_PAD 1024
#define INV_RFF_SCALAR 0.03125f
#define MEAN_FIELD 25.0f
#define PHI_NT 24   /* K = 1536 (concat hh|hl|lh), BK = 64 */

typedef __attribute__((ext_vector_type(8))) short short8;
typedef __attribute__((ext_vector_type(4))) float f32x4;
typedef __attribute__((ext_vector_type(2))) long long2v;

// ---------- bf16 helpers (RTN-even) ----------
__device__ __forceinline__ unsigned short f32_to_bf16(float f) {
    unsigned u = __float_as_uint(f);
    unsigned r = 0x7FFFu + ((u >> 16) & 1u);
    return (unsigned short)((u + r) >> 16);
}
__device__ __forceinline__ float bf16_to_f32(unsigned short h) {
    return __uint_as_float(((unsigned)h) << 16);
}
__device__ __forceinline__ unsigned char f32_to_fp8(float x) {
    __hip_fp8_e4m3 q(x);           // OCP e4m3fn, HW RNE convert
    return (unsigned char)q.__x;
}

// fp8 permuted packing within each 64-element k-block:
// pos(k) = (k & ~63) + quad*16 + s*8 + j   (quad=(k>>3)&3, s=(k>>5)&1, j=k&7)
__device__ __forceinline__ int perm64(int k) {
    return (k & ~63) | (((k >> 3) & 3) << 4) | (((k >> 5) & 1) << 3) | (k & 7);
}

// ---- bf16 staging, K=64 tile (pred): 1024 chunks, q = rt*128 + c*16 + r ----
__device__ __forceinline__ void stage_tile64(const unsigned short* __restrict__ X,
                                             int r0, int k0, unsigned char* lds,
                                             int w, int lane) {
    #pragma unroll
    for (int h = 0; h < 4; ++h) {
        int qb = h * 256 + w * 64;
        int q = qb + lane;
        int rt = q >> 7, c = (q >> 4) & 7, r = q & 15;
        const void* g = X + (size_t)(r0 + rt * 16 + r) * RFF + k0 + c * 8;
        __builtin_amdgcn_global_load_lds(
            (const __attribute__((address_space(1))) void*)g,
            (__attribute__((address_space(3))) void*)(lds + qb * 16),
            16, 0, 0);
    }
}

// ---- fp8 staging, K=128-byte tile (diag) ----
__device__ __forceinline__ void stage_tile8(const unsigned char* __restrict__ X,
                                            int r0, int k0b, unsigned char* lds,
                                            int w, int lane) {
    #pragma unroll
    for (int h = 0; h < 4; ++h) {
        int qb = h * 256 + w * 64;
        int q = qb + lane;
        int rt = q >> 7, c = (q >> 4) & 7, r = q & 15;
        const void* g = X + (size_t)(r0 + rt * 16 + r) * RFF + k0b + c * 16;
        __builtin_amdgcn_global_load_lds(
            (const __attribute__((address_space(1))) void*)g,
            (__attribute__((address_space(3))) void*)(lds + qb * 16),
            16, 0, 0);
    }
}

// ---------------- conversion kernels ----------------
__global__ __launch_bounds__(256) void conv_split_kernel(
    const float* __restrict__ X, unsigned short* __restrict__ H,
    unsigned short* __restrict__ L, int n4)
{
    int i = blockIdx.x * 256 + threadIdx.x;
    if (i >= n4) return;
    float4 v = ((const float4*)X)[i];
    ushort4 h, l;
    h.x = f32_to_bf16(v.x); l.x = f32_to_bf16(v.x - bf16_to_f32(h.x));
    h.y = f32_to_bf16(v.y); l.y = f32_to_bf16(v.y - bf16_to_f32(h.y));
    h.z = f32_to_bf16(v.z); l.z = f32_to_bf16(v.z - bf16_to_f32(h.z));
    h.w = f32_to_bf16(v.w); l.w = f32_to_bf16(v.w - bf16_to_f32(h.w));
    ((ushort4*)H)[i] = h;
    ((ushort4*)L)[i] = l;
}

__global__ __launch_bounds__(256) void conv_covu8_kernel(
    const float* __restrict__ X, unsigned char* __restrict__ O)
{
    int i = blockIdx.x * 256 + threadIdx.x;   // float4 group
    int base = i * 4;
    int row = base >> 11;          // n
    int col = base & 2047;         // k of first component
    int bn = row >> 7, bk = col >> 7;
    float w = (bk < bn) ? 16.0f : (bk == bn ? 8.0f : 0.0f);
    float4 v = ((const float4*)X)[i];
    float w0 = (col + 0 == row) ? 0.0f : w;
    float w1 = (col + 1 == row) ? 0.0f : w;
    float w2 = (col + 2 == row) ? 0.0f : w;
    float w3 = (col + 3 == row) ? 0.0f : w;
    uchar4 o;
    o.x = f32_to_fp8(v.x * w0); o.y = f32_to_fp8(v.y * w1);
    o.z = f32_to_fp8(v.z * w2); o.w = f32_to_fp8(v.w * w3);
    *(uchar4*)(O + (size_t)row * RFF + perm64(col)) = o;
}

__global__ __launch_bounds__(256) void conv_covd_kernel(
    const float* __restrict__ X, float* __restrict__ Cd)
{
    int i = blockIdx.x * 256 + threadIdx.x;
    if (i < RFF) Cd[i] = X[(size_t)i * RFF + i];
}

__global__ __launch_bounds__(256) void conv_phi8_kernel(
    const unsigned short* __restrict__ Phi16, unsigned char* __restrict__ Phi8)
{
    int i = blockIdx.x * 256 + threadIdx.x;
    int base = i * 4;
    int row = base >> 11;
    int col = base & 2047;
    ushort4 v = ((const ushort4*)Phi16)[i];
    uchar4 o;
    o.x = f32_to_fp8(bf16_to_f32(v.x) * 32.0f);
    o.y = f32_to_fp8(bf16_to_f32(v.y) * 32.0f);
    o.z = f32_to_fp8(bf16_to_f32(v.z) * 32.0f);
    o.w = f32_to_fp8(bf16_to_f32(v.w) * 32.0f);
    *(uchar4*)(Phi8 + (size_t)row * RFF + perm64(col)) = o;
}

__global__ __launch_bounds__(256) void conv_lw_kernel(
    const float* __restrict__ Lw, unsigned short* __restrict__ O)
{
    int i = blockIdx.x * 256 + threadIdx.x;
    int base = i * 4;
    int row = base >> 11;
    ushort4 o;
    if (row < OUT_F) {
        float4 v = ((const float4*)Lw)[i];
        o.x = f32_to_bf16(v.x); o.y = f32_to_bf16(v.y);
        o.z = f32_to_bf16(v.z); o.w = f32_to_bf16(v.w);
    } else {
        o.x = o.y = o.z = o.w = 0;
    }
    ((ushort4*)O)[i] = o;
}

__global__ __launch_bounds__(256) void conv_wt_kernel(
    const float* __restrict__ W, unsigned short* __restrict__ TH,
    unsigned short* __restrict__ TL)
{
    __shared__ float tile[64][65];
    const int tid = threadIdx.x;
    const int n0 = blockIdx.x * 64;
    const int k0 = blockIdx.y * 64;
    #pragma unroll
    for (int i = 0; i < 16; ++i) {
        int e = i * 256 + tid;
        int r = e >> 6, c = e & 63;
        tile[r][c] = W[(size_t)(k0 + r) * RFF + n0 + c];
    }
    __syncthreads();
    #pragma unroll
    for (int i = 0; i < 16; ++i) {
        int e = i * 256 + tid;
        int r = e >> 6, c = e & 63;
        float v = tile[c][r];
        unsigned short h = f32_to_bf16(v);
        unsigned short l = f32_to_bf16(v - bf16_to_f32(h));
        TH[(size_t)(n0 + r) * IN_F + k0 + c] = h;
        TL[(size_t)(n0 + r) * IN_F + k0 + c] = l;
    }
}

// =====================================================================
// Kernel 1: Phi = cos(D@W + b)/32 as ONE bf16 GEMM, K-concat 1536:
//   A' = [Dh | Dh | Dl], B' = [Wh | Wl | Wh]  (B^T layout)
// 256x256 tile, BK=64, 512 thr (8 waves 2Mx4N), 4 phases per K-tile.
// Round-2 fixes vs round-1:
//  * NO memory-clobber asm in hot loop (clobber asm forces SIInsertWaitcnts
//    to emit full vmcnt(0)/lgkmcnt(0) drains -> per-phase drain0 plateau).
//    Sync = bare s_barrier + sched_barrier(0) pins; counted vmcnt(4) only.
//  * Each fragment read ONCE per K-tile (24 ds_read_b128/wave/tile, was 48):
//    P1 reads fa(mh0)+fb0, P2 reads fb1, P3 reads fa(mh1), P4 reads none;
//    fb0/fb1 live across phases in registers.
// =====================================================================

__device__ __forceinline__ void gload16u(const void* g, unsigned short* lds) {
    __builtin_amdgcn_global_load_lds(
        (const __attribute__((address_space(1))) void*)g,
        (__attribute__((address_space(3))) void*)lds, 16, 0, 0);
}

// A-group: 64 rows (quarter Qa of half h), full BK=64. 1 load/thread.
__device__ __forceinline__ void stageA_g(const unsigned short* __restrict__ src,
                                         int r0, int kk, unsigned short* ldsbuf,
                                         int Qa, int h, int w, int lane) {
    int q   = w * 64 + lane;
    int RTl = h * 8 + Qa * 4 + (q >> 7);
    int c   = (q >> 4) & 7, r = q & 15;
    const void* g = src + (size_t)(r0 + RTl * 16 + r) * IN_F + kk + c * 8;
    int RTu = h * 8 + Qa * 4 + (w >> 1);
    int cu  = (w & 1) * 4;
    gload16u(g, ldsbuf + RTu * 1024 + cu * 128);
}

// B-group: the 64 rows (of half h) consumed by quadrant nh.
__device__ __forceinline__ void stageB_g(const unsigned short* __restrict__ src,
                                         int cc0, int kk, unsigned short* ldsbuf,
                                         int nh, int h, int w, int lane) {
    int q    = w * 64 + lane;
    int i    = q >> 7;                              // uniform per wave
    int RTp  = (i >> 1) * 4 + nh * 2 + (i & 1);
    int c    = (q >> 4) & 7, r = q & 15;
    const void* g = src + (size_t)(cc0 + h * 128 + RTp * 16 + r) * IN_F + kk + c * 8;
    int iu   = w >> 1;
    int RTpu = (iu >> 1) * 4 + nh * 2 + (iu & 1);
    int RTu  = h * 8 + RTpu;
    int cu   = (w & 1) * 4;
    gload16u(g, ldsbuf + RTu * 1024 + cu * 128);
}

#define SB0() __builtin_amdgcn_sched_barrier(0)
#define BARRIER() do { SB0(); __builtin_amdgcn_s_barrier(); SB0(); } while (0)
#define WAITVM(N) do { asm volatile("s_waitcnt vmcnt(" #N ")"); SB0(); } while (0)

#define READ_FA(FA, mh) do {                                                  \
    _Pragma("unroll")                                                         \
    for (int i_ = 0; i_ < 4; ++i_) {                                          \
        FA[i_][0] = *(const short8*)(A + (wm * 8 + (mh) * 4 + i_) * 1024      \
                                       + quad * 128 + ln * 8);                \
        FA[i_][1] = *(const short8*)(A + (wm * 8 + (mh) * 4 + i_) * 1024      \
                                       + 512 + quad * 128 + ln * 8);          \
    } } while (0)

#define READ_FB(FB, nh) do {                                                  \
    _Pragma("unroll")                                                         \
    for (int j_ = 0; j_ < 2; ++j_) {                                          \
        FB[j_][0] = *(const short8*)(B + (wn * 4 + (nh) * 2 + j_) * 1024      \
                                       + quad * 128 + ln * 8);                \
        FB[j_][1] = *(const short8*)(B + (wn * 4 + (nh) * 2 + j_) * 1024      \
                                       + 512 + quad * 128 + ln * 8);          \
    } } while (0)

#define MFMA16(MH, NH, FA, FB) do {                                           \
    __builtin_amdgcn_s_setprio(1);                                            \
    _Pragma("unroll")                                                         \
    for (int s_ = 0; s_ < 2; ++s_)                                            \
        _Pragma("unroll")                                                     \
        for (int i_ = 0; i_ < 4; ++i_)                                        \
            _Pragma("unroll")                                                 \
            for (int j_ = 0; j_ < 2; ++j_)                                    \
                acc[(MH) * 4 + i_][(NH) * 2 + j_] =                           \
                    __builtin_amdgcn_mfma_f32_16x16x32_bf16(                  \
                        FA[i_][s_], FB[j_][s_],                               \
                        acc[(MH) * 4 + i_][(NH) * 2 + j_], 0, 0, 0);          \
    __builtin_amdgcn_s_setprio(0);                                            \
} while (0)

__global__ __launch_bounds__(512, 2) void phi_mfma8p_kernel(
    const unsigned short* __restrict__ Dh, const unsigned short* __restrict__ Dl,
    const unsigned short* __restrict__ Wth, const unsigned short* __restrict__ Wtl,
    const float* __restrict__ bias, unsigned short* __restrict__ Phi)
{
    __shared__ unsigned short ldsA[2 * 16384];   // 64 KiB (2 bufs x 256x64 bf16)
    __shared__ unsigned short ldsB[2 * 16384];   // 64 KiB
    const int tid = threadIdx.x;
    const int w = tid >> 6, lane = tid & 63;
    const int wm = w >> 2, wn = w & 3;
    const int quad = lane >> 4, ln = lane & 15;

    // XCD-aware: 4x2 XCD grid, each XCD owns an 8r x 4c rectangle of blocks
    const int bid = blockIdx.x;
    const int xcd = bid & 7, idx = bid >> 3;
    const int rb = (xcd >> 1) * 8 + (idx & 7);
    const int cb = (xcd & 1) * 4 + (idx >> 3);
    const int r0 = rb * 256;
    const int c0 = cb * 256;

    f32x4 acc[8][4];
    #pragma unroll
    for (int i = 0; i < 8; ++i)
        #pragma unroll
        for (int j = 0; j < 4; ++j)
            acc[i][j] = (f32x4)(0.0f);

    // ---- prologue: tile 0 complete (8 calls) + tile 1 A-mh0 + B-nh0 ----
    stageA_g(Dh,  r0, 0, ldsA, 0, 0, w, lane);
    stageA_g(Dh,  r0, 0, ldsA, 0, 1, w, lane);
    stageA_g(Dh,  r0, 0, ldsA, 1, 0, w, lane);
    stageA_g(Dh,  r0, 0, ldsA, 1, 1, w, lane);
    stageB_g(Wth, c0, 0, ldsB, 0, 0, w, lane);
    stageB_g(Wth, c0, 0, ldsB, 0, 1, w, lane);
    stageB_g(Wth, c0, 0, ldsB, 1, 0, w, lane);
    stageB_g(Wth, c0, 0, ldsB, 1, 1, w, lane);
    stageA_g(Dh,  r0, 64, ldsA + 16384, 0, 0, w, lane);
    stageA_g(Dh,  r0, 64, ldsA + 16384, 0, 1, w, lane);
    stageB_g(Wth, c0, 64, ldsB + 16384, 0, 0, w, lane);
    stageB_g(Wth, c0, 64, ldsB + 16384, 0, 1, w, lane);
    WAITVM(4);       // tile 0 landed; tile 1's A-mh0/B-nh0 remain in flight
    BARRIER();

    for (int t = 0; t < PHI_NT - 1; ++t) {
        const int buf = t & 1;
        const unsigned short* A = ldsA + buf * 16384;
        const unsigned short* B = ldsB + buf * 16384;
        unsigned short* curA = ldsA + buf * 16384;          // tile t+2 target
        unsigned short* curB = ldsB + buf * 16384;
        unsigned short* othA = ldsA + (buf ^ 1) * 16384;    // tile t+1 target
        unsigned short* othB = ldsB + (buf ^ 1) * 16384;
        const bool has2 = (t + 2) < PHI_NT;
        const int k1 = (t + 1) * 64, k2 = (t + 2) * 64;
        const int kk1 = k1 & 511, kk2 = k2 & 511;
        const unsigned short* A1 = (k1 >= 1024) ? Dl : Dh;
        const unsigned short* B1 = (k1 >= 1024) ? Wth : (k1 >= 512 ? Wtl : Wth);
        const unsigned short* A2 = (k2 >= 1024) ? Dl : Dh;
        const unsigned short* B2 = (k2 >= 1024) ? Wth : (k2 >= 512 ? Wtl : Wth);

        short8 fa[4][2], fb0[2][2], fb1[2][2];

        // P1: read fa(mh0)+fb0(nh0); stage t+1 A-mh1 -> oth (free since t-1.P3)
        READ_FA(fa, 0);
        READ_FB(fb0, 0);
        stageA_g(A1, r0, kk1, othA, 1, 0, w, lane);
        stageA_g(A1, r0, kk1, othA, 1, 1, w, lane);
        BARRIER();
        MFMA16(0, 0, fa, fb0);
        BARRIER();

        // P2: read fb1(nh1); stage t+1 B-nh1 -> oth
        READ_FB(fb1, 1);
        stageB_g(B1, c0, kk1, othB, 1, 0, w, lane);
        stageB_g(B1, c0, kk1, othB, 1, 1, w, lane);
        BARRIER();
        MFMA16(0, 1, fa, fb1);
        BARRIER();

        // P3: read fa(mh1); stage t+2 A-mh0 -> cur (freed by P1's mid barrier)
        READ_FA(fa, 1);
        if (has2) { stageA_g(A2, r0, kk2, curA, 0, 0, w, lane);
                    stageA_g(A2, r0, kk2, curA, 0, 1, w, lane); }
        BARRIER();
        MFMA16(1, 0, fa, fb0);
        BARRIER();

        // P4: stage t+2 B-nh0 -> cur; counted wait (t+1 fully landed,
        // t+2's 4 loads stay in flight across the barrier)
        if (has2) { stageB_g(B2, c0, kk2, curB, 0, 0, w, lane);
                    stageB_g(B2, c0, kk2, curB, 0, 1, w, lane);
                    WAITVM(4); }
        else      { WAITVM(0); }
        BARRIER();
        MFMA16(1, 1, fa, fb1);
        BARRIER();
    }

    // ---- peeled last tile: all data resident, vmcnt == 0 ----
    {
        // free drain (nothing outstanding) + IR-level ordering pin for the
        // only tile whose phases contain no staging calls
        asm volatile("" ::: "memory");
        const unsigned short* A = ldsA + ((PHI_NT - 1) & 1) * 16384;
        const unsigned short* B = ldsB + ((PHI_NT - 1) & 1) * 16384;
        short8 fa[4][2], fb0[2][2], fb1[2][2];
        READ_FA(fa, 0);
        READ_FB(fb0, 0);
        READ_FB(fb1, 1);
        MFMA16(0, 0, fa, fb0);
        MFMA16(0, 1, fa, fb1);
        READ_FA(fa, 1);
        MFMA16(1, 0, fa, fb0);
        MFMA16(1, 1, fa, fb1);
    }

    // ---- epilogue: z -> cos(z)/32 -> bf16 ----
    float bv[4];
    #pragma unroll
    for (int nt = 0; nt < 4; ++nt)
        bv[nt] = bias[c0 + wn * 64 + nt * 16 + ln];
    #pragma unroll
    for (int mt = 0; mt < 8; ++mt)
        #pragma unroll
        for (int nt = 0; nt < 4; ++nt) {
            int col = c0 + wn * 64 + nt * 16 + ln;
            #pragma unroll
            for (int reg = 0; reg < 4; ++reg) {
                int row = r0 + wm * 128 + mt * 16 + quad * 4 + reg;
                float z = acc[mt][nt][reg] + bv[nt];
                float p = __cosf(z) * INV_RFF_SCALAR;
                Phi[(size_t)row * RFF + col] = f32_to_bf16(p);
            }
        }
}

// ------- Kernel 2: diag via fp8 (off-diag) + exact diagonal; triangular K -------
__global__ __launch_bounds__(256) void diag8_kernel(
    const unsigned char* __restrict__ Phi8, const unsigned char* __restrict__ CovU8,
    const unsigned short* __restrict__ Phi16, const float* __restrict__ Cd,
    float* __restrict__ diag)
{
    __shared__ __align__(16) unsigned char ldsA[16384];
    __shared__ __align__(16) unsigned char ldsB[16384];
    const int tid = threadIdx.x;
    const int w = tid >> 6, lane = tid & 63;
    const int wm = w >> 1, wn = w & 1;
    const int quad = lane >> 4, ln = lane & 15;
    const int J = 15 - blockIdx.x;
    const int r0 = blockIdx.y * 128;
    const int c0 = J * 128;
    const int kmax = (J + 1) * 128;

    f32x4 acc[4][4];
    #pragma unroll
    for (int i = 0; i < 4; ++i)
        #pragma unroll
        for (int j = 0; j < 4; ++j)
            acc[i][j] = (f32x4)(0.0f);

    for (int k0 = 0; k0 < kmax; k0 += 128) {
        __syncthreads();
        stage_tile8(Phi8,  r0, k0, ldsA, w, lane);
        stage_tile8(CovU8, c0, k0, ldsB, w, lane);
        __syncthreads();

        #pragma unroll
        for (int kb = 0; kb < 2; ++kb) {
            long2v fa[4], fb[4];
            #pragma unroll
            for (int t = 0; t < 4; ++t) {
                fa[t] = *(const long2v*)(ldsA + (((wm * 4 + t) * 128 + (kb * 4 + quad) * 16 + ln) << 4));
                fb[t] = *(const long2v*)(ldsB + (((wn * 4 + t) * 128 + (kb * 4 + quad) * 16 + ln) << 4));
            }
            #pragma unroll
            for (int mt = 0; mt < 4; ++mt)
                #pragma unroll
                for (int nt = 0; nt < 4; ++nt)
                    acc[mt][nt] = __builtin_amdgcn_mfma_f32_16x16x32_fp8_fp8(
                        fa[mt].x, fb[nt].x, acc[mt][nt], 0, 0, 0);
            #pragma unroll
            for (int mt = 0; mt < 4; ++mt)
                #pragma unroll
                for (int nt = 0; nt < 4; ++nt)
                    acc[mt][nt] = __builtin_amdgcn_mfma_f32_16x16x32_fp8_fp8(
                        fa[mt].y, fb[nt].y, acc[mt][nt], 0, 0, 0);
        }
    }

    float cd[4];
    #pragma unroll
    for (int nt = 0; nt < 4; ++nt)
        cd[nt] = 256.0f * Cd[c0 + wn * 64 + nt * 16 + ln];
    #pragma unroll
    for (int mt = 0; mt < 4; ++mt) {
        float psum[4] = {0.f, 0.f, 0.f, 0.f};
        #pragma unroll
        for (int nt = 0; nt < 4; ++nt) {
            int col = c0 + wn * 64 + nt * 16 + ln;
            #pragma unroll
            for (int reg = 0; reg < 4; ++reg) {
                int row = r0 + wm * 64 + mt * 16 + quad * 4 + reg;
                float pv = bf16_to_f32(Phi16[(size_t)row * RFF + col]);
                psum[reg] = fmaf(fmaf(cd[nt], pv, acc[mt][nt][reg]), pv, psum[reg]);
            }
        }
        #pragma unroll
        for (int off = 1; off < 16; off <<= 1)
            #pragma unroll
            for (int reg = 0; reg < 4; ++reg)
                psum[reg] += __shfl_xor(psum[reg], off, 16);
        if (ln == 0) {
            #pragma unroll
            for (int reg = 0; reg < 4; ++reg) {
                int row = r0 + wm * 64 + mt * 16 + quad * 4 + reg;
                atomicAdd(&diag[row], psum[reg] * (1.0f / 256.0f));
            }
        }
    }
}

// ---- Kernel 3: out = (Phi@LwT + Lb) / sqrt(1+25*diag), bf16, K-step 64 ----
__global__ __launch_bounds__(256) void pred_mfma_kernel(
    const unsigned short* __restrict__ Phi, const unsigned short* __restrict__ Lw,
    const float* __restrict__ Lb, const float* __restrict__ diag,
    float* __restrict__ out)
{
    __shared__ __align__(16) unsigned char ldsA[16384];
    __shared__ __align__(16) unsigned char ldsB[16384];
    const int tid = threadIdx.x;
    const int w = tid >> 6, lane = tid & 63;
    const int wm = w >> 1, wn = w & 1;
    const int quad = lane >> 4, ln = lane & 15;
    const int r0 = blockIdx.y * 128;
    const int c0 = blockIdx.x * 128;

    f32x4 acc[4][4];
    #pragma unroll
    for (int i = 0; i < 4; ++i)
        #pragma unroll
        for (int j = 0; j < 4; ++j)
            acc[i][j] = (f32x4)(0.0f);

    for (int k0 = 0; k0 < RFF; k0 += 64) {
        __syncthreads();
        stage_tile64(Phi, r0, k0, ldsA, w, lane);
        stage_tile64(Lw,  c0, k0, ldsB, w, lane);
        __syncthreads();

        #pragma unroll
        for (int s = 0; s < 2; ++s) {
            short8 fa[4], fb[4];
            #pragma unroll
            for (int t = 0; t < 4; ++t) {
                fa[t] = *(const short8*)(ldsA + (((wm * 4 + t) * 128 + (s * 4 + quad) * 16 + ln) << 4));
                fb[t] = *(const short8*)(ldsB + (((wn * 4 + t) * 128 + (s * 4 + quad) * 16 + ln) << 4));
            }
            #pragma unroll
            for (int mt = 0; mt < 4; ++mt)
                #pragma unroll
                for (int nt = 0; nt < 4; ++nt)
                    acc[mt][nt] = __builtin_amdgcn_mfma_f32_16x16x32_bf16(
                        fa[mt], fb[nt], acc[mt][nt], 0, 0, 0);
        }
    }

    #pragma unroll
    for (int mt = 0; mt < 4; ++mt) {
        float s[4];
        #pragma unroll
        for (int reg = 0; reg < 4; ++reg) {
            int row = r0 + wm * 64 + mt * 16 + quad * 4 + reg;
            s[reg] = 1.0f / sqrtf(1.0f + MEAN_FIELD * diag[row]);
        }
        #pragma unroll
        for (int nt = 0; nt < 4; ++nt) {
            int col = c0 + wn * 64 + nt * 16 + ln;
            if (col < OUT_F) {
                float bv = Lb[col];
                #pragma unroll
                for (int reg = 0; reg < 4; ++reg) {
                    int row = r0 + wm * 64 + mt * 16 + quad * 4 + reg;
                    out[(size_t)row * OUT_F + col] = (acc[mt][nt][reg] + bv) * s[reg];
                }
            }
        }
    }
}

extern "C" void kernel_launch(void* const* d_in, const int* in_sizes, int n_in,
                              void* d_out, int out_size, void* d_ws, size_t ws_size,
                              hipStream_t stream) {
    const float* D    = (const float*)d_in[0];
    const float* W    = (const float*)d_in[1];
    const float* bias = (const float*)d_in[2];
    const float* Lw   = (const float*)d_in[3];
    const float* Lb   = (const float*)d_in[4];
    const float* cov  = (const float*)d_in[5];
    float* out = (float*)d_out;

    char* p = (char*)d_ws;
    unsigned short* Phi16 = (unsigned short*)p;  p += (size_t)N_ROWS * RFF * 2;   // 32 MiB
    unsigned char*  Phi8  = (unsigned char*)p;   // alias of Dh+Dl region (16 MiB)
    unsigned short* Dh    = (unsigned short*)p;  p += (size_t)N_ROWS * IN_F * 2;  // 8 MiB
    unsigned short* Dl    = (unsigned short*)p;  p += (size_t)N_ROWS * IN_F * 2;  // 8 MiB
    unsigned short* Wth   = (unsigned short*)p;  p += (size_t)RFF * IN_F * 2;     // 2 MiB
    unsigned short* Wtl   = (unsigned short*)p;  p += (size_t)RFF * IN_F * 2;     // 2 MiB
    unsigned short* Lw16  = (unsigned short*)p;  p += (size_t)OUT_PAD * RFF * 2;  // 4 MiB
    unsigned char*  CovU8 = (unsigned char*)p;                                    // 4 MiB used
    float*          Cd    = (float*)(p + (size_t)RFF * RFF);                      // 8 KiB (in pad)
    p += (size_t)RFF * RFF * 2;                                                   // 8 MiB region
    float* diag           = (float*)p;                                            // 32 KiB

    hipMemsetAsync(diag, 0, N_ROWS * sizeof(float), stream);

    dim3 blk(256);
    conv_split_kernel<<<dim3((N_ROWS * IN_F / 4 + 255) / 256), blk, 0, stream>>>(D, Dh, Dl, N_ROWS * IN_F / 4);
    conv_wt_kernel<<<dim3(RFF / 64, IN_F / 64), blk, 0, stream>>>(W, Wth, Wtl);
    conv_lw_kernel<<<dim3(OUT_PAD * RFF / 4 / 256), blk, 0, stream>>>(Lw, Lw16);
    conv_covu8_kernel<<<dim3(RFF * RFF / 4 / 256), blk, 0, stream>>>(cov, CovU8);
    conv_covd_kernel<<<dim3(RFF / 256), blk, 0, stream>>>(cov, Cd);

    phi_mfma8p_kernel<<<dim3(256), dim3(512), 0, stream>>>(Dh, Dl, Wth, Wtl, bias, Phi16);
    conv_phi8_kernel<<<dim3(N_ROWS * RFF / 4 / 256), blk, 0, stream>>>(Phi16, Phi8);

    diag8_kernel<<<dim3(16, N_ROWS / 128), blk, 0, stream>>>(Phi8, CovU8, Phi16, Cd, diag);
    pred_mfma_kernel<<<dim3(OUT_PAD / 128, N_ROWS / 128), blk, 0, stream>>>(Phi16, Lw16, Lb, diag, out);
}